// Round 2
// baseline (3801.533 us; speedup 1.0000x reference)
//
#include <hip/hip_runtime.h>
#include <hip/hip_bf16.h>

namespace {

constexpr int NTOK  = 3137;          // 1 + 16*196
constexpr int DIM   = 512;
constexpr int NH    = 8;
constexpr int DH    = 64;
constexpr int BH    = 64;            // BATCH*NH
constexpr int MROWS = 8 * NTOK;      // 25096
constexpr int MF    = 266;           // NB_FEATURES
constexpr int NSP   = 196;
constexpr int SEQK  = 197;
constexpr int NG    = 1024;          // BH * f

constexpr float DN     = 0.35355339059327379f;  // 64^-0.25
constexpr float HDN2   = 0.0625f;               // 0.5 * 64^-0.5
constexpr float RATIO  = 0.0613139368f;         // 266^-0.5
constexpr float EPSV   = 1.0e-4f;
constexpr float QSCALE = 0.125f;                // 64^-0.5

__device__ __forceinline__ float b2f(unsigned short u) {
  union { unsigned int i; float f; } cv;
  cv.i = ((unsigned int)u) << 16;
  return cv.f;
}
__device__ __forceinline__ unsigned short f2b(float f) {
  __hip_bfloat16 h = __float2bfloat16(f);
  union { __hip_bfloat16 h; unsigned short u; } cv;
  cv.h = h;
  return cv.u;
}

// ---------------- qkv = x @ W_qkv (fp32 VALU), scatter bf16 q/k/v -----------
__global__ __launch_bounds__(256) void k_qkv(
    const float* __restrict__ x,   // [MROWS][512]
    const float* __restrict__ w,   // [512][1536]
    unsigned short* __restrict__ qb, unsigned short* __restrict__ kb,
    unsigned short* __restrict__ vb)
{
  __shared__ alignas(16) float AsT[16][132];
  __shared__ alignas(16) float Bs[16][132];
  const int bm = blockIdx.x, bn = blockIdx.y;
  const int tid = threadIdx.x;
  const int tx = tid & 15, ty = tid >> 4;
  const int row0 = bm * 128, col0 = bn * 128;
  float acc[8][8] = {};
  for (int k0 = 0; k0 < 512; k0 += 16) {
    {
      const int r = tid >> 1, c0 = (tid & 1) * 8;
      const int gr = row0 + r;
      if (gr < MROWS) {
        const float* src = x + (size_t)gr * 512 + k0 + c0;
        const float4 v0 = *(const float4*)src;
        const float4 v1 = *(const float4*)(src + 4);
        AsT[c0 + 0][r] = v0.x; AsT[c0 + 1][r] = v0.y;
        AsT[c0 + 2][r] = v0.z; AsT[c0 + 3][r] = v0.w;
        AsT[c0 + 4][r] = v1.x; AsT[c0 + 5][r] = v1.y;
        AsT[c0 + 6][r] = v1.z; AsT[c0 + 7][r] = v1.w;
      } else {
        #pragma unroll
        for (int j = 0; j < 8; ++j) AsT[c0 + j][r] = 0.f;
      }
    }
    {
      const int r = tid >> 4, c0 = (tid & 15) * 8;
      const float* src = w + (size_t)(k0 + r) * 1536 + col0 + c0;
      const float4 v0 = *(const float4*)src;
      const float4 v1 = *(const float4*)(src + 4);
      Bs[r][c0 + 0] = v0.x; Bs[r][c0 + 1] = v0.y;
      Bs[r][c0 + 2] = v0.z; Bs[r][c0 + 3] = v0.w;
      Bs[r][c0 + 4] = v1.x; Bs[r][c0 + 5] = v1.y;
      Bs[r][c0 + 6] = v1.z; Bs[r][c0 + 7] = v1.w;
    }
    __syncthreads();
    #pragma unroll
    for (int kk = 0; kk < 16; ++kk) {
      float a[8], b[8];
      *(float4*)&a[0] = *(const float4*)&AsT[kk][ty * 8];
      *(float4*)&a[4] = *(const float4*)&AsT[kk][ty * 8 + 4];
      *(float4*)&b[0] = *(const float4*)&Bs[kk][tx * 8];
      *(float4*)&b[4] = *(const float4*)&Bs[kk][tx * 8 + 4];
      #pragma unroll
      for (int i = 0; i < 8; ++i)
        #pragma unroll
        for (int j = 0; j < 8; ++j)
          acc[i][j] += a[i] * b[j];
    }
    __syncthreads();
  }
  #pragma unroll
  for (int i = 0; i < 8; ++i) {
    const int gr = row0 + ty * 8 + i;
    if (gr < MROWS) {
      const int bb = gr / NTOK, n = gr - bb * NTOK;
      #pragma unroll
      for (int j = 0; j < 8; ++j) {
        const int gc = col0 + tx * 8 + j;
        const int which = gc >> 9;
        const int col = gc & 511;
        const int hh = col >> 6, d = col & 63;
        const size_t off = (size_t)((bb * NH + hh) * NTOK + n) * DH + d;
        const float vv = acc[i][j];
        if (which == 0)      qb[off] = f2b(vv * QSCALE);
        else if (which == 1) kb[off] = f2b(vv);
        else                 vb[off] = f2b(vv);
      }
    }
  }
}

// ---------------- cls-token softmax attention -------------------------------
__global__ __launch_bounds__(256) void k_cls(
    const unsigned short* __restrict__ qb, const unsigned short* __restrict__ kb,
    const unsigned short* __restrict__ vb, unsigned short* __restrict__ attnb)
{
  __shared__ float sim[NTOK];
  __shared__ float qv[DH];
  __shared__ float sred[4], sred2[4];
  __shared__ float pbuf[4][DH];
  const int bh = blockIdx.x, tid = threadIdx.x;
  const int wv = tid >> 6, dcl = tid & 63;
  const unsigned short* ks = kb + (size_t)bh * NTOK * DH;
  const unsigned short* vs = vb + (size_t)bh * NTOK * DH;
  if (tid < DH) qv[tid] = b2f(qb[(size_t)bh * NTOK * DH + tid]);
  __syncthreads();
  float lmax = -1e30f;
  for (int j = tid; j < NTOK; j += 256) {
    const unsigned short* kr = ks + (size_t)j * DH;
    float dot = 0.f;
    #pragma unroll
    for (int d = 0; d < DH; ++d) dot += qv[d] * b2f(kr[d]);
    sim[j] = dot;
    lmax = fmaxf(lmax, dot);
  }
  #pragma unroll
  for (int off = 32; off; off >>= 1) lmax = fmaxf(lmax, __shfl_xor(lmax, off));
  if ((tid & 63) == 0) sred[wv] = lmax;
  __syncthreads();
  const float mx = fmaxf(fmaxf(sred[0], sred[1]), fmaxf(sred[2], sred[3]));
  float lsum = 0.f;
  for (int j = tid; j < NTOK; j += 256) {
    const float p = expf(sim[j] - mx);
    sim[j] = p;
    lsum += p;
  }
  #pragma unroll
  for (int off = 32; off; off >>= 1) lsum += __shfl_xor(lsum, off);
  __syncthreads();
  if ((tid & 63) == 0) sred2[wv] = lsum;
  __syncthreads();
  const float tot = sred2[0] + sred2[1] + sred2[2] + sred2[3];
  float accv = 0.f;
  for (int j = wv; j < NTOK; j += 4) accv += sim[j] * b2f(vs[(size_t)j * DH + dcl]);
  pbuf[wv][dcl] = accv;
  __syncthreads();
  if (tid < DH) {
    const float o = (pbuf[0][tid] + pbuf[1][tid] + pbuf[2][tid] + pbuf[3][tid]) / tot;
    const int bb = bh >> 3, hh = bh & 7;
    attnb[((size_t)bb * NTOK + 0) * DIM + hh * DH + tid] = f2b(o);
  }
}

// ---------------- global max of dn*(k . proj_m) over all keys ---------------
__global__ __launch_bounds__(256) void k_keymax(
    const unsigned short* __restrict__ kb, const float* __restrict__ proj,
    float* __restrict__ pmax)
{
  __shared__ unsigned short projT[64 * 268];
  __shared__ float kvec[DH];
  __shared__ float sred[4];
  const int g = blockIdx.x, bh = g >> 4, c = g & 15;
  const int tid = threadIdx.x;
  for (int idx = tid; idx < MF * DH; idx += 256) {
    const int m = idx >> 6, d = idx & 63;
    projT[d * 268 + m] = f2b(proj[idx]);
  }
  const unsigned short* ksrc = kb + (size_t)bh * NTOK * DH;
  float lmax = -1e30f;
  for (int n = 0; n < SEQK; ++n) {
    __syncthreads();
    if (tid < DH) {
      const int node = (n == 0) ? 0 : (1 + c * NSP + (n - 1));
      kvec[tid] = b2f(ksrc[(size_t)node * DH + tid]);
    }
    __syncthreads();
    {
      float dot = 0.f;
      #pragma unroll
      for (int d = 0; d < DH; ++d) dot += kvec[d] * b2f(projT[d * 268 + tid]);
      lmax = fmaxf(lmax, DN * dot);
    }
    if (tid < MF - 256) {
      float dot1 = 0.f;
      #pragma unroll
      for (int d = 0; d < DH; ++d) dot1 += kvec[d] * b2f(projT[d * 268 + 256 + tid]);
      lmax = fmaxf(lmax, DN * dot1);
    }
  }
  #pragma unroll
  for (int off = 32; off; off >>= 1) lmax = fmaxf(lmax, __shfl_xor(lmax, off));
  if ((tid & 63) == 0) sred[tid >> 6] = lmax;
  __syncthreads();
  if (tid == 0) pmax[g] = fmaxf(fmaxf(sred[0], sred[1]), fmaxf(sred[2], sred[3]));
}

__global__ __launch_bounds__(256) void k_maxred(
    const float* __restrict__ pmax, float* __restrict__ gmax)
{
  __shared__ float sred[4];
  float v = -1e30f;
  for (int i = threadIdx.x; i < NG; i += 256) v = fmaxf(v, pmax[i]);
  #pragma unroll
  for (int off = 32; off; off >>= 1) v = fmaxf(v, __shfl_xor(v, off));
  if ((threadIdx.x & 63) == 0) sred[threadIdx.x >> 6] = v;
  __syncthreads();
  if (threadIdx.x == 0)
    gmax[0] = fmaxf(fmaxf(sred[0], sred[1]), fmaxf(sred[2], sred[3]));
}

// ------- fused per-group: context (regs) + ksum (regs) + query + output -----
// Thread (wv = tid>>6, dcl = tid&63) owns ctx rows m = wv + 4*i (i<67), col dcl.
__global__ __launch_bounds__(256) void k_fused(
    const unsigned short* __restrict__ qb, const unsigned short* __restrict__ kb,
    const unsigned short* __restrict__ vb, const float* __restrict__ proj,
    const float* __restrict__ gmaxp, unsigned short* __restrict__ attnb)
{
  __shared__ unsigned short projT[64 * 268];
  __shared__ float kvec[DH], vrow[DH];
  __shared__ float prow[MF];
  __shared__ float sred[4], sred2[4];
  __shared__ float pbuf[4][DH];
  __shared__ float diag_s;
  const int g = blockIdx.x, bh = g >> 4, c = g & 15;
  const int bb = bh >> 3, hh = bh & 7;
  const int tid = threadIdx.x;
  const int wv = tid >> 6, dcl = tid & 63;
  const float gm = gmaxp[0];
  for (int idx = tid; idx < MF * DH; idx += 256) {
    const int m = idx >> 6, d = idx & 63;
    projT[d * 268 + m] = f2b(proj[idx]);
  }
  const unsigned short* ksrc = kb + (size_t)bh * NTOK * DH;
  const unsigned short* vsrc = vb + (size_t)bh * NTOK * DH;
  const unsigned short* qsrc = qb + (size_t)bh * NTOK * DH;

  float ctx_r[67];
  #pragma unroll
  for (int i = 0; i < 67; ++i) ctx_r[i] = 0.f;
  float ks0 = 0.f, ks1 = 0.f;

  // ---------------- phase A: keys -> ctx_r, ks ----------------
  for (int n = 0; n < SEQK; ++n) {
    __syncthreads();
    const int node = (n == 0) ? 0 : (1 + c * NSP + (n - 1));
    float kval = 0.f;
    if (tid < DH)          { kval = b2f(ksrc[(size_t)node * DH + tid]); kvec[tid] = kval; }
    else if (tid < 2 * DH) { vrow[tid - DH] = b2f(vsrc[(size_t)node * DH + (tid - DH)]); }
    __syncthreads();
    if (tid < DH) {
      float s = kval * kval;
      #pragma unroll
      for (int off = 32; off; off >>= 1) s += __shfl_xor(s, off);
      if (tid == 0) diag_s = HDN2 * s;
    }
    __syncthreads();
    {
      float dot = 0.f;
      #pragma unroll
      for (int d = 0; d < DH; ++d) dot += kvec[d] * b2f(projT[d * 268 + tid]);
      const float kp = RATIO * (expf(DN * dot - diag_s - gm) + EPSV);
      prow[tid] = kp;
      ks0 += kp;
      if (tid < MF - 256) {
        float dot1 = 0.f;
        #pragma unroll
        for (int d = 0; d < DH; ++d) dot1 += kvec[d] * b2f(projT[d * 268 + 256 + tid]);
        const float kp1 = RATIO * (expf(DN * dot1 - diag_s - gm) + EPSV);
        prow[256 + tid] = kp1;
        ks1 += kp1;
      }
    }
    __syncthreads();
    const float vr = vrow[dcl];
    #pragma unroll
    for (int i = 0; i < 67; ++i) {
      const int m = wv + 4 * i;
      if (m < MF) ctx_r[i] += prow[m] * vr;
    }
  }

  // ---------------- phase B: queries -> output rows ----------------
  for (int nq = 0; nq < NSP; ++nq) {
    __syncthreads();
    const int node = 1 + c * NSP + nq;
    float qval = 0.f;
    if (tid < DH) { qval = b2f(qsrc[(size_t)node * DH + tid]); kvec[tid] = qval; }
    __syncthreads();
    if (tid < DH) {
      float s = qval * qval;
      #pragma unroll
      for (int off = 32; off; off >>= 1) s += __shfl_xor(s, off);
      if (tid == 0) diag_s = HDN2 * s;
    }
    float dot0 = 0.f;
    #pragma unroll
    for (int d = 0; d < DH; ++d) dot0 += kvec[d] * b2f(projT[d * 268 + tid]);
    const float dd0 = DN * dot0;
    float dd1 = -1e30f;
    if (tid < MF - 256) {
      float dot1 = 0.f;
      #pragma unroll
      for (int d = 0; d < DH; ++d) dot1 += kvec[d] * b2f(projT[d * 268 + 256 + tid]);
      dd1 = DN * dot1;
    }
    float lm = fmaxf(dd0, dd1);
    #pragma unroll
    for (int off = 32; off; off >>= 1) lm = fmaxf(lm, __shfl_xor(lm, off));
    if ((tid & 63) == 0) sred[wv] = lm;
    __syncthreads();
    const float rmax = fmaxf(fmaxf(sred[0], sred[1]), fmaxf(sred[2], sred[3]));
    const float dg = diag_s;
    const float e0 = RATIO * (expf(dd0 - dg - rmax) + EPSV);
    prow[tid] = e0;
    float dpart = e0 * ks0;
    if (tid < MF - 256) {
      const float e1 = RATIO * (expf(dd1 - dg - rmax) + EPSV);
      prow[256 + tid] = e1;
      dpart += e1 * ks1;
    }
    #pragma unroll
    for (int off = 32; off; off >>= 1) dpart += __shfl_xor(dpart, off);
    if ((tid & 63) == 0) sred2[wv] = dpart;
    __syncthreads();
    float part = 0.f;
    #pragma unroll
    for (int i = 0; i < 67; ++i) {
      const int m = wv + 4 * i;
      if (m < MF) part += prow[m] * ctx_r[i];
    }
    pbuf[wv][dcl] = part;
    __syncthreads();
    if (tid < DH) {
      const float dsum = sred2[0] + sred2[1] + sred2[2] + sred2[3];
      const float o = (pbuf[0][tid] + pbuf[1][tid] + pbuf[2][tid] + pbuf[3][tid]) / dsum;
      attnb[((size_t)bb * NTOK + node) * DIM + hh * DH + tid] = f2b(o);
    }
  }
}

// ---------------- out = attn(bf16) @ W_out(fp32) -> fp32 --------------------
__global__ __launch_bounds__(256) void k_out(
    const unsigned short* __restrict__ a,   // bf16 [MROWS][512]
    const float* __restrict__ w,            // fp32 [512][512]
    float* __restrict__ out)                // fp32 [MROWS][512]
{
  __shared__ alignas(16) float AsT[16][132];
  __shared__ alignas(16) float Bs[16][132];
  const int bm = blockIdx.x, bn = blockIdx.y;
  const int tid = threadIdx.x;
  const int tx = tid & 15, ty = tid >> 4;
  const int row0 = bm * 128, col0 = bn * 128;
  float acc[8][8] = {};
  for (int k0 = 0; k0 < 512; k0 += 16) {
    {
      const int r = tid >> 1, c0 = (tid & 1) * 8;
      const int gr = row0 + r;
      if (gr < MROWS) {
        const unsigned short* src = a + (size_t)gr * 512 + k0 + c0;
        #pragma unroll
        for (int j = 0; j < 8; ++j) AsT[c0 + j][r] = b2f(src[j]);
      } else {
        #pragma unroll
        for (int j = 0; j < 8; ++j) AsT[c0 + j][r] = 0.f;
      }
    }
    {
      const int r = tid >> 4, c0 = (tid & 15) * 8;
      const float* src = w + (size_t)(k0 + r) * 512 + col0 + c0;
      const float4 v0 = *(const float4*)src;
      const float4 v1 = *(const float4*)(src + 4);
      Bs[r][c0 + 0] = v0.x; Bs[r][c0 + 1] = v0.y;
      Bs[r][c0 + 2] = v0.z; Bs[r][c0 + 3] = v0.w;
      Bs[r][c0 + 4] = v1.x; Bs[r][c0 + 5] = v1.y;
      Bs[r][c0 + 6] = v1.z; Bs[r][c0 + 7] = v1.w;
    }
    __syncthreads();
    #pragma unroll
    for (int kk = 0; kk < 16; ++kk) {
      float av[8], bv[8];
      *(float4*)&av[0] = *(const float4*)&AsT[kk][ty * 8];
      *(float4*)&av[4] = *(const float4*)&AsT[kk][ty * 8 + 4];
      *(float4*)&bv[0] = *(const float4*)&Bs[kk][tx * 8];
      *(float4*)&bv[4] = *(const float4*)&Bs[kk][tx * 8 + 4];
      #pragma unroll
      for (int i = 0; i < 8; ++i)
        #pragma unroll
        for (int j = 0; j < 8; ++j)
          acc[i][j] += av[i] * bv[j];
    }
    __syncthreads();
  }
  #pragma unroll
  for (int i = 0; i < 8; ++i) {
    const int gr = row0 + ty * 8 + i;
    if (gr < MROWS) {
      #pragma unroll
      for (int j = 0; j < 8; ++j) {
        out[(size_t)gr * 512 + col0 + tx * 8 + j] = acc[i][j];
      }
    }
  }
}

}  // namespace

extern "C" void kernel_launch(void* const* d_in, const int* in_sizes, int n_in,
                              void* d_out, int out_size, void* d_ws, size_t ws_size,
                              hipStream_t stream) {
  (void)in_sizes; (void)n_in; (void)out_size; (void)ws_size;
  const float* x    = (const float*)d_in[0];
  const float* wqkv = (const float*)d_in[1];
  const float* wout = (const float*)d_in[2];
  const float* proj = (const float*)d_in[3];
  float* out = (float*)d_out;

  const size_t QKV = (size_t)BH * NTOK * DH;  // 12,849,152 elements
  unsigned short* qb    = (unsigned short*)d_ws;
  unsigned short* kb    = qb + QKV;
  unsigned short* vb    = kb + QKV;
  unsigned short* attnb = vb + QKV;
  float* pmax = (float*)(attnb + QKV);   // byte offset 4*QKV*2 = 102,793,216 (16B aligned)
  float* gmax = pmax + NG;
  // total ws use: ~98.05 MB

  const dim3 blk(256);
  k_qkv    <<<dim3(197, 12), blk, 0, stream>>>(x, wqkv, qb, kb, vb);
  k_cls    <<<dim3(BH),      blk, 0, stream>>>(qb, kb, vb, attnb);
  k_keymax <<<dim3(NG),      blk, 0, stream>>>(kb, proj, pmax);
  k_maxred <<<dim3(1),       blk, 0, stream>>>(pmax, gmax);
  k_fused  <<<dim3(NG),      blk, 0, stream>>>(qb, kb, vb, proj, gmax, attnb);
  k_out    <<<dim3(197, 4),  blk, 0, stream>>>(attnb, wout, out);
}